// Round 2
// baseline (2029.182 us; speedup 1.0000x reference)
//
#include <hip/hip_runtime.h>
#include <math.h>

constexpr int BB  = 32;
constexpr int SQL = 2048;
constexpr int SKL = 2048;
constexpr int DD  = 64;
constexpr int TQ  = 8;             // q rows per block
constexpr int NCK = SKL / 64;      // 32 chunks of 64 cols

__global__ __launch_bounds__(256, 3) void sdpa_fwd(
    const float* __restrict__ q,
    const float* __restrict__ k,
    const int*   __restrict__ mask,
    float*       __restrict__ out)
{
    __shared__ float s_q[TQ][DD];          // q tile, pre-scaled by 1/8

    const int t  = threadIdx.x;
    const int tx = t & 63;                 // lane = column within chunk
    const int ty = t >> 6;                 // wave id 0..3
    const int b  = blockIdx.y;
    const int r0 = blockIdx.x * TQ;

    // ---- stage q tile once (scaled by 1/8; exact pow2, no accuracy loss)
    if (t < 128) {
        const int row = t >> 4;            // 0..7
        const int d0  = (t & 15) << 2;     // 0,4,...,60
        float4 v = *reinterpret_cast<const float4*>(
            q + ((size_t)b * SQL + (size_t)(r0 + row)) * DD + d0);
        v.x *= 0.125f; v.y *= 0.125f; v.z *= 0.125f; v.w *= 0.125f;
        *reinterpret_cast<float4*>(&s_q[row][d0]) = v;
    }
    __syncthreads();                       // only barrier in the kernel

    float sc0[NCK], sc1[NCK];              // register-resident scores (64 VGPR)
    float pm0 = -INFINITY, pm1 = -INFINITY;

    const float* kb  = k + ((size_t)b * SKL + (size_t)tx) * DD;
    const int*   mb0 = mask + ((size_t)b * SQL + (size_t)(r0 + ty)) * SKL + tx;
    const int*   mb1 = mb0 + (size_t)4 * SKL;

    #pragma unroll
    for (int ck = 0; ck < NCK; ++ck) {
        const float* kr = kb + (size_t)ck * 64 * DD;   // this lane's k row
        const int m0 = mb0[ck * 64];
        const int m1 = mb1[ck * 64];
        float a0 = 0.f, a1 = 0.f;
        #pragma unroll
        for (int dv = 0; dv < DD / 4; ++dv) {
            const float4 kv = *reinterpret_cast<const float4*>(kr + dv * 4);
            const float4 q0 = *reinterpret_cast<const float4*>(&s_q[ty    ][dv * 4]);
            const float4 q1 = *reinterpret_cast<const float4*>(&s_q[ty + 4][dv * 4]);
            a0 = fmaf(q0.x, kv.x, a0); a0 = fmaf(q0.y, kv.y, a0);
            a0 = fmaf(q0.z, kv.z, a0); a0 = fmaf(q0.w, kv.w, a0);
            a1 = fmaf(q1.x, kv.x, a1); a1 = fmaf(q1.y, kv.y, a1);
            a1 = fmaf(q1.z, kv.z, a1); a1 = fmaf(q1.w, kv.w, a1);
        }
        const float v0 = m0 ? a0 : -INFINITY;
        const float v1 = m1 ? a1 : -INFINITY;
        sc0[ck] = v0; pm0 = fmaxf(pm0, v0);
        sc1[ck] = v1; pm1 = fmaxf(pm1, v1);
    }

    // ---- softmax row ty (owned entirely by wave ty)
    {
        float m = pm0;
        #pragma unroll
        for (int off = 32; off > 0; off >>= 1)
            m = fmaxf(m, __shfl_xor(m, off, 64));
        float sum = 0.f;
        #pragma unroll
        for (int ck = 0; ck < NCK; ++ck) {
            const float e = __expf(sc0[ck] - m);
            sc0[ck] = e;
            sum += e;
        }
        #pragma unroll
        for (int off = 32; off > 0; off >>= 1)
            sum += __shfl_xor(sum, off, 64);
        const float rinv = 1.0f / sum;
        float* ob = out + ((size_t)b * SQL + (size_t)(r0 + ty)) * SKL + tx;
        #pragma unroll
        for (int ck = 0; ck < NCK; ++ck)
            ob[ck * 64] = sc0[ck] * rinv;
    }

    // ---- softmax row ty+4
    {
        float m = pm1;
        #pragma unroll
        for (int off = 32; off > 0; off >>= 1)
            m = fmaxf(m, __shfl_xor(m, off, 64));
        float sum = 0.f;
        #pragma unroll
        for (int ck = 0; ck < NCK; ++ck) {
            const float e = __expf(sc1[ck] - m);
            sc1[ck] = e;
            sum += e;
        }
        #pragma unroll
        for (int off = 32; off > 0; off >>= 1)
            sum += __shfl_xor(sum, off, 64);
        const float rinv = 1.0f / sum;
        float* ob = out + ((size_t)b * SQL + (size_t)(r0 + ty + 4)) * SKL + tx;
        #pragma unroll
        for (int ck = 0; ck < NCK; ++ck)
            ob[ck * 64] = sc1[ck] * rinv;
    }
}

extern "C" void kernel_launch(void* const* d_in, const int* in_sizes, int n_in,
                              void* d_out, int out_size, void* d_ws, size_t ws_size,
                              hipStream_t stream) {
    const float* q    = (const float*)d_in[0];
    const float* k    = (const float*)d_in[1];
    const int*   mask = (const int*)d_in[2];
    float*       out  = (float*)d_out;

    dim3 grid(SQL / TQ, BB);   // 256 x 32 = 8192 blocks
    sdpa_fwd<<<grid, dim3(256), 0, stream>>>(q, k, mask, out);
}

// Round 3
// 720.997 us; speedup vs baseline: 2.8144x; 2.8144x over previous
//
#include <hip/hip_runtime.h>
#include <math.h>

constexpr int BB  = 32;
constexpr int SQL = 2048;
constexpr int SKL = 2048;
constexpr int DD  = 64;

using f32x4   = __attribute__((ext_vector_type(4))) float;
using bfrag   = __attribute__((ext_vector_type(8))) short;   // 8 bf16 = 4 VGPR

static __device__ __forceinline__ unsigned short f2bf(float x) {
    unsigned u = __float_as_uint(x);
    u = u + 0x7FFFu + ((u >> 16) & 1u);          // round-nearest-even
    return (unsigned short)(u >> 16);
}
static __device__ __forceinline__ float bf2f(unsigned short h) {
    return __uint_as_float((unsigned)h << 16);
}

// ---- prepass 1: mask int32 -> bitmask (1 bit/elem) via wave ballot
__global__ __launch_bounds__(256) void compress_mask(
    const int* __restrict__ m, unsigned* __restrict__ bm, long long n)
{
    long long i0 = (long long)blockIdx.x * blockDim.x + threadIdx.x;
    long long stride = (long long)gridDim.x * blockDim.x;
    for (long long i = i0; i < n; i += stride) {
        unsigned long long bits = __ballot(m[i] != 0);
        if ((threadIdx.x & 31) == 0)
            bm[i >> 5] = (unsigned)(bits >> ((threadIdx.x & 32) ? 32 : 0));
    }
}

// ---- prepass 2: k fp32 -> bf16 hi/lo planes (same [B][SK][D] layout)
__global__ __launch_bounds__(256) void split_k(
    const float* __restrict__ k, unsigned short* __restrict__ kh,
    unsigned short* __restrict__ kl, int n)
{
    int i0 = blockIdx.x * blockDim.x + threadIdx.x;
    int stride = gridDim.x * blockDim.x;
    for (int i = i0; i < n; i += stride) {
        float x = k[i];
        unsigned short h = f2bf(x);
        kh[i] = h;
        kl[i] = f2bf(x - bf2f(h));
    }
}

// ---- main: per wave one 16-row q tile; two passes over all 2048 cols.
// MFMA 16x16x32 bf16, split-bf16 for fp32-level accuracy. No LDS, no
// score storage (recompute in pass B), no runtime-indexed arrays.
template<bool PRE>
__global__ __launch_bounds__(256, 4) void sdpa_mfma(
    const float* __restrict__ q, const float* __restrict__ k,
    const int* __restrict__ mask, const unsigned* __restrict__ bm,
    const unsigned short* __restrict__ kh, const unsigned short* __restrict__ kl,
    float* __restrict__ out)
{
    const int t  = threadIdx.x;
    const int l  = t & 63;
    const int w  = t >> 6;
    const int b  = blockIdx.y;
    const int qb = blockIdx.x * 64 + w * 16;     // wave's q-row base
    const int lr = l & 15;                       // A row / B,C col within tile
    const int lg = l >> 4;                       // k-group / C row-group

    // ---- A fragments (q), scale 1/8 folded, hi/lo split. Built once.
    bfrag ah0, al0, ah1, al1;
    {
        const float* qp = q + ((size_t)b * SQL + (size_t)(qb + lr)) * DD + lg * 8;
        #pragma unroll
        for (int j = 0; j < 8; ++j) {
            float x0 = qp[j]      * 0.125f;
            float x1 = qp[32 + j] * 0.125f;
            unsigned short h0 = f2bf(x0), h1 = f2bf(x1);
            ah0[j] = (short)h0; al0[j] = (short)f2bf(x0 - bf2f(h0));
            ah1[j] = (short)h1; al1[j] = (short)f2bf(x1 - bf2f(h1));
        }
    }

    // per-row-slot base pointers (static-indexed arrays of 4)
    const unsigned* bmr[4];
    const int*      mr[4];
    float*          orow[4];
    #pragma unroll
    for (int i = 0; i < 4; ++i) {
        const size_t row = (size_t)b * SQL + (size_t)(qb + lg * 4 + i);
        if (PRE) bmr[i] = bm + row * (SKL / 32);
        else     mr[i]  = mask + row * SKL;
        orow[i] = out + row * SKL;
    }
    const unsigned short* khb = PRE ? kh + (size_t)b * SKL * DD : nullptr;
    const unsigned short* klb = PRE ? kl + (size_t)b * SKL * DD : nullptr;
    const float*          kb  = k + (size_t)b * SKL * DD;

    float psum[4] = {0.f, 0.f, 0.f, 0.f};

    // =================== PASS A: row sums ===================
    for (int nt = 0; nt < SKL / 16; ++nt) {
        const int n0 = nt * 16;
        bfrag bh0, bl0, bh1, bl1;
        if constexpr (PRE) {
            const unsigned short* p0 = khb + (size_t)(n0 + lr) * DD + lg * 8;
            const unsigned short* p1 = klb + (size_t)(n0 + lr) * DD + lg * 8;
            bh0 = *reinterpret_cast<const bfrag*>(p0);
            bh1 = *reinterpret_cast<const bfrag*>(p0 + 32);
            bl0 = *reinterpret_cast<const bfrag*>(p1);
            bl1 = *reinterpret_cast<const bfrag*>(p1 + 32);
        } else {
            const float* kp = kb + (size_t)(n0 + lr) * DD + lg * 8;
            #pragma unroll
            for (int j = 0; j < 8; ++j) {
                float x0 = kp[j], x1 = kp[32 + j];
                unsigned short h0 = f2bf(x0), h1 = f2bf(x1);
                bh0[j] = (short)h0; bl0[j] = (short)f2bf(x0 - bf2f(h0));
                bh1[j] = (short)h1; bl1[j] = (short)f2bf(x1 - bf2f(h1));
            }
        }
        f32x4 acc = {0.f, 0.f, 0.f, 0.f};
        acc = __builtin_amdgcn_mfma_f32_16x16x32_bf16(ah0, bl0, acc, 0, 0, 0);
        acc = __builtin_amdgcn_mfma_f32_16x16x32_bf16(al0, bh0, acc, 0, 0, 0);
        acc = __builtin_amdgcn_mfma_f32_16x16x32_bf16(ah0, bh0, acc, 0, 0, 0);
        acc = __builtin_amdgcn_mfma_f32_16x16x32_bf16(ah1, bl1, acc, 0, 0, 0);
        acc = __builtin_amdgcn_mfma_f32_16x16x32_bf16(al1, bh1, acc, 0, 0, 0);
        acc = __builtin_amdgcn_mfma_f32_16x16x32_bf16(ah1, bh1, acc, 0, 0, 0);

        #pragma unroll
        for (int i = 0; i < 4; ++i) {
            float bit;
            if constexpr (PRE)
                bit = (float)((bmr[i][n0 >> 5] >> ((n0 & 31) + lr)) & 1u);
            else
                bit = (mr[i][n0 + lr] != 0) ? 1.f : 0.f;
            psum[i] += bit * __expf(acc[i]);
        }
    }

    // ---- reduce row sums across the 16 lanes sharing each row
    float rinv[4];
    #pragma unroll
    for (int i = 0; i < 4; ++i) {
        float s = psum[i];
        s += __shfl_xor(s, 1, 64);
        s += __shfl_xor(s, 2, 64);
        s += __shfl_xor(s, 4, 64);
        s += __shfl_xor(s, 8, 64);
        rinv[i] = 1.0f / s;
    }

    // =================== PASS B: recompute & write ===================
    for (int nt = 0; nt < SKL / 16; ++nt) {
        const int n0 = nt * 16;
        bfrag bh0, bl0, bh1, bl1;
        if constexpr (PRE) {
            const unsigned short* p0 = khb + (size_t)(n0 + lr) * DD + lg * 8;
            const unsigned short* p1 = klb + (size_t)(n0 + lr) * DD + lg * 8;
            bh0 = *reinterpret_cast<const bfrag*>(p0);
            bh1 = *reinterpret_cast<const bfrag*>(p0 + 32);
            bl0 = *reinterpret_cast<const bfrag*>(p1);
            bl1 = *reinterpret_cast<const bfrag*>(p1 + 32);
        } else {
            const float* kp = kb + (size_t)(n0 + lr) * DD + lg * 8;
            #pragma unroll
            for (int j = 0; j < 8; ++j) {
                float x0 = kp[j], x1 = kp[32 + j];
                unsigned short h0 = f2bf(x0), h1 = f2bf(x1);
                bh0[j] = (short)h0; bl0[j] = (short)f2bf(x0 - bf2f(h0));
                bh1[j] = (short)h1; bl1[j] = (short)f2bf(x1 - bf2f(h1));
            }
        }
        f32x4 acc = {0.f, 0.f, 0.f, 0.f};
        acc = __builtin_amdgcn_mfma_f32_16x16x32_bf16(ah0, bl0, acc, 0, 0, 0);
        acc = __builtin_amdgcn_mfma_f32_16x16x32_bf16(al0, bh0, acc, 0, 0, 0);
        acc = __builtin_amdgcn_mfma_f32_16x16x32_bf16(ah0, bh0, acc, 0, 0, 0);
        acc = __builtin_amdgcn_mfma_f32_16x16x32_bf16(ah1, bl1, acc, 0, 0, 0);
        acc = __builtin_amdgcn_mfma_f32_16x16x32_bf16(al1, bh1, acc, 0, 0, 0);
        acc = __builtin_amdgcn_mfma_f32_16x16x32_bf16(ah1, bh1, acc, 0, 0, 0);

        #pragma unroll
        for (int i = 0; i < 4; ++i) {
            float bit;
            if constexpr (PRE)
                bit = (float)((bmr[i][n0 >> 5] >> ((n0 & 31) + lr)) & 1u);
            else
                bit = (mr[i][n0 + lr] != 0) ? 1.f : 0.f;
            orow[i][n0 + lr] = bit * __expf(acc[i]) * rinv[i];
        }
    }
}

extern "C" void kernel_launch(void* const* d_in, const int* in_sizes, int n_in,
                              void* d_out, int out_size, void* d_ws, size_t ws_size,
                              hipStream_t stream) {
    const float* q    = (const float*)d_in[0];
    const float* k    = (const float*)d_in[1];
    const int*   mask = (const int*)d_in[2];
    float*       out  = (float*)d_out;

    const size_t BM_BYTES = (size_t)BB * SQL * (SKL / 32) * 4;   // 16.78 MB
    const size_t KE       = (size_t)BB * SKL * DD;               // 4.19M elems
    const size_t NEED     = BM_BYTES + KE * 4;                   // + kh/kl bf16

    dim3 grid(SQL / 64, BB);   // 32 x 32 blocks, 4 waves each

    if (ws_size >= NEED) {
        unsigned*       bm = (unsigned*)d_ws;
        unsigned short* khp = (unsigned short*)((char*)d_ws + BM_BYTES);
        unsigned short* klp = khp + KE;
        compress_mask<<<4096, 256, 0, stream>>>(mask, bm,
                                                (long long)BB * SQL * SKL);
        split_k<<<1024, 256, 0, stream>>>(k, khp, klp, (int)KE);
        sdpa_mfma<true><<<grid, 256, 0, stream>>>(q, k, mask, bm, khp, klp, out);
    } else {
        sdpa_mfma<false><<<grid, 256, 0, stream>>>(q, k, mask, nullptr,
                                                   nullptr, nullptr, out);
    }
}

// Round 4
// 444.430 us; speedup vs baseline: 4.5658x; 1.6223x over previous
//
#include <hip/hip_runtime.h>
#include <math.h>

constexpr int BB  = 32;
constexpr int SQL = 2048;
constexpr int SKL = 2048;
constexpr int DD  = 64;
constexpr int CW  = 256;          // cols per wave
constexpr int NT  = CW / 16;      // 16 col-tiles per wave

using f32x4 = __attribute__((ext_vector_type(4))) float;
using bfrag = __attribute__((ext_vector_type(8))) short;   // 8 bf16 = 4 VGPR

static __device__ __forceinline__ unsigned short f2bf(float x) {
    unsigned u = __float_as_uint(x);
    u = u + 0x7FFFu + ((u >> 16) & 1u);          // round-nearest-even
    return (unsigned short)(u >> 16);
}
static __device__ __forceinline__ float bf2f(unsigned short h) {
    return __uint_as_float((unsigned)h << 16);
}

// ---- prepass: k fp32 -> bf16 hi/lo planes (same [B][SK][D] layout)
__global__ __launch_bounds__(256) void split_k(
    const float* __restrict__ k, unsigned short* __restrict__ kh,
    unsigned short* __restrict__ kl, int n)
{
    int i0 = blockIdx.x * blockDim.x + threadIdx.x;
    int stride = gridDim.x * blockDim.x;
    for (int i = i0; i < n; i += stride) {
        float x = k[i];
        unsigned short h = f2bf(x);
        kh[i] = h;
        kl[i] = f2bf(x - bf2f(h));
    }
}

// ---- main: block = 8 waves = 16 q-rows; wave w owns cols [w*256,(w+1)*256).
// Single pass over k: masked exp values kept in registers as packed bf16.
template<bool PRE>
__global__ __launch_bounds__(512, 3) void sdpa_fused(
    const float* __restrict__ q, const float* __restrict__ k,
    const int* __restrict__ mask,
    const unsigned short* __restrict__ kh, const unsigned short* __restrict__ kl,
    float* __restrict__ out)
{
    __shared__ float s_red[8][16];

    const int t  = threadIdx.x;
    const int l  = t & 63;
    const int w  = t >> 6;
    const int b  = blockIdx.y;
    const int r0 = blockIdx.x * 16;
    const int lr = l & 15;
    const int lg = l >> 4;
    const int c0 = w * CW;

    // ---- A fragments (q rows r0..r0+15), scale 1/8 folded, hi/lo split
    bfrag ah0, al0, ah1, al1;
    {
        const float* qp = q + ((size_t)b * SQL + (size_t)(r0 + lr)) * DD + lg * 8;
        #pragma unroll
        for (int j = 0; j < 8; ++j) {
            float x0 = qp[j]      * 0.125f;
            float x1 = qp[32 + j] * 0.125f;
            unsigned short h0 = f2bf(x0), h1 = f2bf(x1);
            ah0[j] = (short)h0; al0[j] = (short)f2bf(x0 - bf2f(h0));
            ah1[j] = (short)h1; al1[j] = (short)f2bf(x1 - bf2f(h1));
        }
    }

    // per-row-slot pointers (this lane's 4 C rows), offset to this wave's cols
    const int* mrow[4];
    float*     orow[4];
    #pragma unroll
    for (int i = 0; i < 4; ++i) {
        const size_t row = (size_t)b * SQL + (size_t)(r0 + lg * 4 + i);
        mrow[i] = mask + row * SKL + c0 + lr;
        orow[i] = out  + row * SKL + c0 + lr;
    }

    const unsigned short* khb = PRE ? kh + ((size_t)b * SKL + c0) * DD : nullptr;
    const unsigned short* klb = PRE ? kl + ((size_t)b * SKL + c0) * DD : nullptr;
    const float*          kb  = k + ((size_t)b * SKL + (size_t)c0) * DD;

    unsigned sc[NT * 2];              // packed bf16 exp values (32 VGPR)
    float psum[4] = {0.f, 0.f, 0.f, 0.f};

    #pragma unroll
    for (int nt = 0; nt < NT; ++nt) {
        const int n0 = nt * 16;
        bfrag bh0, bl0, bh1, bl1;
        if constexpr (PRE) {
            const unsigned short* p0 = khb + (size_t)(n0 + lr) * DD + lg * 8;
            const unsigned short* p1 = klb + (size_t)(n0 + lr) * DD + lg * 8;
            bh0 = *reinterpret_cast<const bfrag*>(p0);
            bh1 = *reinterpret_cast<const bfrag*>(p0 + 32);
            bl0 = *reinterpret_cast<const bfrag*>(p1);
            bl1 = *reinterpret_cast<const bfrag*>(p1 + 32);
        } else {
            const float* kp = kb + (size_t)(n0 + lr) * DD + lg * 8;
            #pragma unroll
            for (int j = 0; j < 8; ++j) {
                float x0 = kp[j], x1 = kp[32 + j];
                unsigned short h0 = f2bf(x0), h1 = f2bf(x1);
                bh0[j] = (short)h0; bl0[j] = (short)f2bf(x0 - bf2f(h0));
                bh1[j] = (short)h1; bl1[j] = (short)f2bf(x1 - bf2f(h1));
            }
        }
        f32x4 acc = {0.f, 0.f, 0.f, 0.f};
        acc = __builtin_amdgcn_mfma_f32_16x16x32_bf16(ah0, bl0, acc, 0, 0, 0);
        acc = __builtin_amdgcn_mfma_f32_16x16x32_bf16(al0, bh0, acc, 0, 0, 0);
        acc = __builtin_amdgcn_mfma_f32_16x16x32_bf16(ah0, bh0, acc, 0, 0, 0);
        acc = __builtin_amdgcn_mfma_f32_16x16x32_bf16(ah1, bl1, acc, 0, 0, 0);
        acc = __builtin_amdgcn_mfma_f32_16x16x32_bf16(al1, bh1, acc, 0, 0, 0);
        acc = __builtin_amdgcn_mfma_f32_16x16x32_bf16(ah1, bh1, acc, 0, 0, 0);

        float e[4];
        #pragma unroll
        for (int i = 0; i < 4; ++i) {
            const float v = (mrow[i][n0] != 0) ? __expf(acc[i]) : 0.f;
            e[i] = v;
            psum[i] += v;
        }
        sc[2 * nt    ] = (unsigned)f2bf(e[0]) | ((unsigned)f2bf(e[1]) << 16);
        sc[2 * nt + 1] = (unsigned)f2bf(e[2]) | ((unsigned)f2bf(e[3]) << 16);
    }

    // ---- row sums: shfl within 16-lane row groups, LDS across 8 waves
    #pragma unroll
    for (int i = 0; i < 4; ++i) {
        float s = psum[i];
        s += __shfl_xor(s, 1, 64);
        s += __shfl_xor(s, 2, 64);
        s += __shfl_xor(s, 4, 64);
        s += __shfl_xor(s, 8, 64);
        psum[i] = s;
    }
    if (lr == 0) {
        #pragma unroll
        for (int i = 0; i < 4; ++i)
            s_red[w][lg * 4 + i] = psum[i];
    }
    __syncthreads();

    float rinv[4];
    #pragma unroll
    for (int i = 0; i < 4; ++i) {
        float tot = 0.f;
        #pragma unroll
        for (int ww = 0; ww < 8; ++ww)
            tot += s_red[ww][lg * 4 + i];
        rinv[i] = 1.0f / tot;
    }

    // ---- unpack, normalize, store
    #pragma unroll
    for (int nt = 0; nt < NT; ++nt) {
        const int n0 = nt * 16;
        const unsigned p01 = sc[2 * nt];
        const unsigned p23 = sc[2 * nt + 1];
        orow[0][n0] = bf2f((unsigned short)(p01 & 0xffffu))  * rinv[0];
        orow[1][n0] = bf2f((unsigned short)(p01 >> 16))      * rinv[1];
        orow[2][n0] = bf2f((unsigned short)(p23 & 0xffffu))  * rinv[2];
        orow[3][n0] = bf2f((unsigned short)(p23 >> 16))      * rinv[3];
    }
}

extern "C" void kernel_launch(void* const* d_in, const int* in_sizes, int n_in,
                              void* d_out, int out_size, void* d_ws, size_t ws_size,
                              hipStream_t stream) {
    const float* q    = (const float*)d_in[0];
    const float* k    = (const float*)d_in[1];
    const int*   mask = (const int*)d_in[2];
    float*       out  = (float*)d_out;

    const size_t KE   = (size_t)BB * SKL * DD;   // 4.19M elems
    const size_t NEED = KE * 4;                  // kh + kl (bf16 each)

    dim3 grid(SQL / 16, BB);   // 128 x 32 = 4096 blocks, 8 waves each

    if (ws_size >= NEED) {
        unsigned short* khp = (unsigned short*)d_ws;
        unsigned short* klp = khp + KE;
        split_k<<<1024, 256, 0, stream>>>(k, khp, klp, (int)KE);
        sdpa_fused<true><<<grid, 512, 0, stream>>>(q, k, mask, khp, klp, out);
    } else {
        sdpa_fused<false><<<grid, 512, 0, stream>>>(q, k, mask, nullptr, nullptr, out);
    }
}

// Round 5
// 411.325 us; speedup vs baseline: 4.9333x; 1.0805x over previous
//
#include <hip/hip_runtime.h>
#include <math.h>

constexpr int BB  = 32;
constexpr int SQL = 2048;
constexpr int SKL = 2048;
constexpr int DD  = 64;
constexpr int CW  = 256;          // cols per wave
constexpr int NT  = CW / 16;      // 16 col-tiles per wave

using f32x4 = __attribute__((ext_vector_type(4))) float;
using bfrag = __attribute__((ext_vector_type(8))) short;   // 8 bf16 = 4 VGPR
using us4   = __attribute__((ext_vector_type(4))) unsigned short;

static __device__ __forceinline__ unsigned short f2bf(float x) {
    unsigned u = __float_as_uint(x);
    u = u + 0x7FFFu + ((u >> 16) & 1u);          // round-nearest-even
    return (unsigned short)(u >> 16);
}
static __device__ __forceinline__ float bf2f(unsigned short h) {
    return __uint_as_float((unsigned)h << 16);
}

// ---- prepass: k fp32 -> bf16 hi/lo planes (same [B][SK][D] layout), float4-wide
__global__ __launch_bounds__(256) void split_k(
    const float* __restrict__ k, unsigned short* __restrict__ kh,
    unsigned short* __restrict__ kl, int n4)
{
    int i0 = blockIdx.x * blockDim.x + threadIdx.x;
    int stride = gridDim.x * blockDim.x;
    for (int i = i0; i < n4; i += stride) {
        f32x4 x = reinterpret_cast<const f32x4*>(k)[i];
        us4 h, lo;
        #pragma unroll
        for (int j = 0; j < 4; ++j) {
            unsigned short hh = f2bf(x[j]);
            h[j]  = hh;
            lo[j] = f2bf(x[j] - bf2f(hh));
        }
        reinterpret_cast<us4*>(kh)[i] = h;
        reinterpret_cast<us4*>(kl)[i] = lo;
    }
}

// ---- main: block = 8 waves = 16 q-rows; wave w owns cols [w*256,(w+1)*256).
// Mask slice staged to LDS (deep, coalesced int4 stream); k frags prefetched.
template<bool PRE>
__global__ __launch_bounds__(512) void sdpa_fused(
    const float* __restrict__ q, const float* __restrict__ k,
    const int* __restrict__ mask,
    const unsigned short* __restrict__ kh, const unsigned short* __restrict__ kl,
    float* __restrict__ out)
{
    __shared__ unsigned char s_mask[8][16][256];   // [wave][row][swizzled col]
    __shared__ float s_red[8][16];

    const int t  = threadIdx.x;
    const int l  = t & 63;
    const int w  = t >> 6;
    const int b  = blockIdx.y;
    const int r0 = blockIdx.x * 16;
    const int lr = l & 15;
    const int lg = l >> 4;
    const int c0 = w * CW;

    // ---- stage this wave's 16x256 mask slice into LDS as bytes.
    // Swizzle: word index = l ^ r  (byte base = (4l) ^ (4r)) -> write 2-way
    // (free), per-tile u8 reads hit 16 distinct banks, same-word broadcast.
    {
        const int* mbase = mask + ((size_t)b * SQL + (size_t)r0) * SKL + c0 + 4 * l;
        #pragma unroll
        for (int r = 0; r < 16; ++r) {
            const int4 v = *reinterpret_cast<const int4*>(mbase + (size_t)r * SKL);
            unsigned pk = (v.x != 0 ? 1u : 0u)
                        | (v.y != 0 ? 0x100u : 0u)
                        | (v.z != 0 ? 0x10000u : 0u)
                        | (v.w != 0 ? 0x1000000u : 0u);
            *reinterpret_cast<unsigned*>(&s_mask[w][r][(4 * l) ^ (r << 2)]) = pk;
        }
    }

    // ---- A fragments (q rows r0..r0+15), scale 1/8 folded, hi/lo split
    bfrag ah0, al0, ah1, al1;
    {
        const float* qp = q + ((size_t)b * SQL + (size_t)(r0 + lr)) * DD + lg * 8;
        const f32x4 x0 = *reinterpret_cast<const f32x4*>(qp);
        const f32x4 x1 = *reinterpret_cast<const f32x4*>(qp + 4);
        const f32x4 y0 = *reinterpret_cast<const f32x4*>(qp + 32);
        const f32x4 y1 = *reinterpret_cast<const f32x4*>(qp + 36);
        #pragma unroll
        for (int j = 0; j < 4; ++j) {
            float a = x0[j] * 0.125f, c = x1[j] * 0.125f;
            float d = y0[j] * 0.125f, e = y1[j] * 0.125f;
            unsigned short h;
            h = f2bf(a); ah0[j]     = (short)h; al0[j]     = (short)f2bf(a - bf2f(h));
            h = f2bf(c); ah0[j + 4] = (short)h; al0[j + 4] = (short)f2bf(c - bf2f(h));
            h = f2bf(d); ah1[j]     = (short)h; al1[j]     = (short)f2bf(d - bf2f(h));
            h = f2bf(e); ah1[j + 4] = (short)h; al1[j + 4] = (short)f2bf(e - bf2f(h));
        }
    }

    float* orow[4];
    #pragma unroll
    for (int i = 0; i < 4; ++i) {
        const size_t row = (size_t)b * SQL + (size_t)(r0 + lg * 4 + i);
        orow[i] = out + row * SKL + c0 + lr;
    }

    const unsigned short* khb = PRE ? kh + ((size_t)b * SKL + c0) * DD : nullptr;
    const unsigned short* klb = PRE ? kl + ((size_t)b * SKL + c0) * DD : nullptr;
    const float*          kb  = k + ((size_t)b * SKL + (size_t)c0) * DD;

#define LOADK(NT_, BH0, BH1, BL0, BL1)                                         \
    do {                                                                       \
        const int _n0 = (NT_) * 16;                                            \
        if constexpr (PRE) {                                                   \
            const unsigned short* _p0 = khb + (size_t)(_n0 + lr) * DD + lg * 8;\
            const unsigned short* _p1 = klb + (size_t)(_n0 + lr) * DD + lg * 8;\
            BH0 = *reinterpret_cast<const bfrag*>(_p0);                        \
            BH1 = *reinterpret_cast<const bfrag*>(_p0 + 32);                   \
            BL0 = *reinterpret_cast<const bfrag*>(_p1);                        \
            BL1 = *reinterpret_cast<const bfrag*>(_p1 + 32);                   \
        } else {                                                               \
            const float* _kp = kb + (size_t)(_n0 + lr) * DD + lg * 8;          \
            _Pragma("unroll")                                                  \
            for (int _j = 0; _j < 8; ++_j) {                                   \
                float _x0 = _kp[_j], _x1 = _kp[32 + _j];                       \
                unsigned short _h0 = f2bf(_x0), _h1 = f2bf(_x1);               \
                BH0[_j] = (short)_h0; BL0[_j] = (short)f2bf(_x0 - bf2f(_h0));  \
                BH1[_j] = (short)_h1; BL1[_j] = (short)f2bf(_x1 - bf2f(_h1));  \
            }                                                                  \
        }                                                                      \
    } while (0)

    unsigned sc[NT * 2];              // packed bf16 exp values (32 VGPR)
    float psum[4] = {0.f, 0.f, 0.f, 0.f};

    bfrag cbh0, cbh1, cbl0, cbl1;
    LOADK(0, cbh0, cbh1, cbl0, cbl1);

    #pragma unroll
    for (int nt = 0; nt < NT; ++nt) {
        const int n0 = nt * 16;
        bfrag nbh0, nbh1, nbl0, nbl1;
        if (nt + 1 < NT) LOADK(nt + 1, nbh0, nbh1, nbl0, nbl1);

        // mask bytes from LDS (conflict-free swizzled reads)
        unsigned char mb[4];
        #pragma unroll
        for (int i = 0; i < 4; ++i) {
            const int row = lg * 4 + i;
            mb[i] = s_mask[w][row][(n0 + lr) ^ (row << 2)];
        }

        f32x4 acc = {0.f, 0.f, 0.f, 0.f};
        acc = __builtin_amdgcn_mfma_f32_16x16x32_bf16(ah0, cbl0, acc, 0, 0, 0);
        acc = __builtin_amdgcn_mfma_f32_16x16x32_bf16(al0, cbh0, acc, 0, 0, 0);
        acc = __builtin_amdgcn_mfma_f32_16x16x32_bf16(ah0, cbh0, acc, 0, 0, 0);
        acc = __builtin_amdgcn_mfma_f32_16x16x32_bf16(ah1, cbl1, acc, 0, 0, 0);
        acc = __builtin_amdgcn_mfma_f32_16x16x32_bf16(al1, cbh1, acc, 0, 0, 0);
        acc = __builtin_amdgcn_mfma_f32_16x16x32_bf16(ah1, cbh1, acc, 0, 0, 0);

        float e[4];
        #pragma unroll
        for (int i = 0; i < 4; ++i) {
            const float v = mb[i] ? __expf(acc[i]) : 0.f;
            e[i] = v;
            psum[i] += v;
        }
        sc[2 * nt    ] = (unsigned)f2bf(e[0]) | ((unsigned)f2bf(e[1]) << 16);
        sc[2 * nt + 1] = (unsigned)f2bf(e[2]) | ((unsigned)f2bf(e[3]) << 16);

        cbh0 = nbh0; cbh1 = nbh1; cbl0 = nbl0; cbl1 = nbl1;
    }
#undef LOADK

    // ---- row sums: shfl within 16-lane row groups, LDS across 8 waves
    #pragma unroll
    for (int i = 0; i < 4; ++i) {
        float s = psum[i];
        s += __shfl_xor(s, 1, 64);
        s += __shfl_xor(s, 2, 64);
        s += __shfl_xor(s, 4, 64);
        s += __shfl_xor(s, 8, 64);
        psum[i] = s;
    }
    if (lr == 0) {
        #pragma unroll
        for (int i = 0; i < 4; ++i)
            s_red[w][lg * 4 + i] = psum[i];
    }
    __syncthreads();

    float rinv[4];
    #pragma unroll
    for (int i = 0; i < 4; ++i) {
        float tot = 0.f;
        #pragma unroll
        for (int ww = 0; ww < 8; ++ww)
            tot += s_red[ww][lg * 4 + i];
        rinv[i] = 1.0f / tot;
    }

    // ---- unpack, normalize, store
    #pragma unroll
    for (int nt = 0; nt < NT; ++nt) {
        const int n0 = nt * 16;
        const unsigned p01 = sc[2 * nt];
        const unsigned p23 = sc[2 * nt + 1];
        orow[0][n0] = bf2f((unsigned short)(p01 & 0xffffu))  * rinv[0];
        orow[1][n0] = bf2f((unsigned short)(p01 >> 16))      * rinv[1];
        orow[2][n0] = bf2f((unsigned short)(p23 & 0xffffu))  * rinv[2];
        orow[3][n0] = bf2f((unsigned short)(p23 >> 16))      * rinv[3];
    }
}

extern "C" void kernel_launch(void* const* d_in, const int* in_sizes, int n_in,
                              void* d_out, int out_size, void* d_ws, size_t ws_size,
                              hipStream_t stream) {
    const float* q    = (const float*)d_in[0];
    const float* k    = (const float*)d_in[1];
    const int*   mask = (const int*)d_in[2];
    float*       out  = (float*)d_out;

    const size_t KE   = (size_t)BB * SKL * DD;   // 4.19M elems
    const size_t NEED = KE * 4;                  // kh + kl (bf16 each)

    dim3 grid(SQL / 16, BB);   // 128 x 32 = 4096 blocks, 8 waves each

    if (ws_size >= NEED) {
        unsigned short* khp = (unsigned short*)d_ws;
        unsigned short* klp = khp + KE;
        split_k<<<1024, 256, 0, stream>>>(k, khp, klp, (int)(KE / 4));
        sdpa_fused<true><<<grid, 512, 0, stream>>>(q, k, mask, khp, klp, out);
    } else {
        sdpa_fused<false><<<grid, 512, 0, stream>>>(q, k, mask, nullptr, nullptr, out);
    }
}

// Round 6
// 397.662 us; speedup vs baseline: 5.1028x; 1.0344x over previous
//
#include <hip/hip_runtime.h>
#include <math.h>

constexpr int BB  = 32;
constexpr int SQL = 2048;
constexpr int SKL = 2048;
constexpr int DD  = 64;
constexpr int CW  = 256;          // cols per wave
constexpr int NT  = CW / 16;      // 16 col-tiles per wave

using f32x4 = __attribute__((ext_vector_type(4))) float;
using bfrag = __attribute__((ext_vector_type(8))) short;   // 8 bf16 = 4 VGPR
using us4   = __attribute__((ext_vector_type(4))) unsigned short;

static __device__ __forceinline__ unsigned short f2bf(float x) {
    unsigned u = __float_as_uint(x);
    u = u + 0x7FFFu + ((u >> 16) & 1u);          // round-nearest-even
    return (unsigned short)(u >> 16);
}
static __device__ __forceinline__ float bf2f(unsigned short h) {
    return __uint_as_float((unsigned)h << 16);
}

// ---- prepass: k fp32 -> bf16 hi/lo planes (same [B][SK][D] layout), float4-wide
__global__ __launch_bounds__(256) void split_k(
    const float* __restrict__ k, unsigned short* __restrict__ kh,
    unsigned short* __restrict__ kl, int n4)
{
    int i0 = blockIdx.x * blockDim.x + threadIdx.x;
    int stride = gridDim.x * blockDim.x;
    for (int i = i0; i < n4; i += stride) {
        f32x4 x = reinterpret_cast<const f32x4*>(k)[i];
        us4 h, lo;
        #pragma unroll
        for (int j = 0; j < 4; ++j) {
            unsigned short hh = f2bf(x[j]);
            h[j]  = hh;
            lo[j] = f2bf(x[j] - bf2f(hh));
        }
        reinterpret_cast<us4*>(kh)[i] = h;
        reinterpret_cast<us4*>(kl)[i] = lo;
    }
}

struct KS { bfrag h0, h1, l0, l1; };

// ---- main: block = 8 waves = 16 q-rows; wave w owns cols [w*256,(w+1)*256).
// 3 independent MFMA acc chains, k prefetch depth 2, mask prefetch depth 1,
// XCD-chunked block swizzle so each XCD streams one batch (k L2-resident).
template<bool PRE>
__global__ __launch_bounds__(512) void sdpa_fused(
    const float* __restrict__ q, const float* __restrict__ k,
    const int* __restrict__ mask,
    const unsigned short* __restrict__ kh, const unsigned short* __restrict__ kl,
    float* __restrict__ out)
{
    __shared__ unsigned char s_mask[8][16][256];   // [wave][row][swizzled col]
    __shared__ float s_red[8][16];

    const int t   = threadIdx.x;
    const int l   = t & 63;
    const int w   = t >> 6;
    const int bid = blockIdx.x;                    // 0..4095
    const int swz = (bid & 7) * 512 + (bid >> 3);  // bijective XCD chunking
    const int b   = swz >> 7;                      // batch
    const int r0  = (swz & 127) * 16;              // q-row base
    const int lr  = l & 15;
    const int lg  = l >> 4;
    const int c0  = w * CW;

    // ---- stage this wave's 16x256 mask slice into LDS as bytes (swizzled)
    {
        const int* mbase = mask + ((size_t)b * SQL + (size_t)r0) * SKL + c0 + 4 * l;
        #pragma unroll
        for (int r = 0; r < 16; ++r) {
            const int4 v = *reinterpret_cast<const int4*>(mbase + (size_t)r * SKL);
            unsigned pk = (v.x != 0 ? 1u : 0u)
                        | (v.y != 0 ? 0x100u : 0u)
                        | (v.z != 0 ? 0x10000u : 0u)
                        | (v.w != 0 ? 0x1000000u : 0u);
            *reinterpret_cast<unsigned*>(&s_mask[w][r][(4 * l) ^ (r << 2)]) = pk;
        }
    }

    // ---- A fragments (q rows r0..r0+15), scale (log2e/8) folded, hi/lo split
    constexpr float QS = 0.18033688011112042f;     // 0.125 * log2(e)
    bfrag ah0, al0, ah1, al1;
    {
        const float* qp = q + ((size_t)b * SQL + (size_t)(r0 + lr)) * DD + lg * 8;
        const f32x4 x0 = *reinterpret_cast<const f32x4*>(qp);
        const f32x4 x1 = *reinterpret_cast<const f32x4*>(qp + 4);
        const f32x4 y0 = *reinterpret_cast<const f32x4*>(qp + 32);
        const f32x4 y1 = *reinterpret_cast<const f32x4*>(qp + 36);
        #pragma unroll
        for (int j = 0; j < 4; ++j) {
            float a = x0[j] * QS, c = x1[j] * QS;
            float d = y0[j] * QS, e = y1[j] * QS;
            unsigned short h;
            h = f2bf(a); ah0[j]     = (short)h; al0[j]     = (short)f2bf(a - bf2f(h));
            h = f2bf(c); ah0[j + 4] = (short)h; al0[j + 4] = (short)f2bf(c - bf2f(h));
            h = f2bf(d); ah1[j]     = (short)h; al1[j]     = (short)f2bf(d - bf2f(h));
            h = f2bf(e); ah1[j + 4] = (short)h; al1[j + 4] = (short)f2bf(e - bf2f(h));
        }
    }

    float* orow[4];
    #pragma unroll
    for (int i = 0; i < 4; ++i) {
        const size_t row = (size_t)b * SQL + (size_t)(r0 + lg * 4 + i);
        orow[i] = out + row * SKL + c0 + lr;
    }

    const unsigned short* khb = PRE ? kh + ((size_t)b * SKL + c0) * DD : nullptr;
    const unsigned short* klb = PRE ? kl + ((size_t)b * SKL + c0) * DD : nullptr;
    const float*          kb  = k + ((size_t)b * SKL + (size_t)c0) * DD;

#define LOADK(TILE, BUF)                                                       \
    do {                                                                       \
        const int _tt = (TILE) > NT - 1 ? NT - 1 : (TILE);                     \
        const int _n0 = _tt * 16;                                              \
        if constexpr (PRE) {                                                   \
            const unsigned short* _p0 = khb + (size_t)(_n0 + lr) * DD + lg * 8;\
            const unsigned short* _p1 = klb + (size_t)(_n0 + lr) * DD + lg * 8;\
            BUF.h0 = *reinterpret_cast<const bfrag*>(_p0);                     \
            BUF.h1 = *reinterpret_cast<const bfrag*>(_p0 + 32);                \
            BUF.l0 = *reinterpret_cast<const bfrag*>(_p1);                     \
            BUF.l1 = *reinterpret_cast<const bfrag*>(_p1 + 32);                \
        } else {                                                               \
            const float* _kp = kb + (size_t)(_n0 + lr) * DD + lg * 8;          \
            _Pragma("unroll")                                                  \
            for (int _j = 0; _j < 8; ++_j) {                                   \
                float _x0 = _kp[_j], _x1 = _kp[32 + _j];                       \
                unsigned short _h0 = f2bf(_x0), _h1 = f2bf(_x1);               \
                BUF.h0[_j] = (short)_h0;                                       \
                BUF.l0[_j] = (short)f2bf(_x0 - bf2f(_h0));                     \
                BUF.h1[_j] = (short)_h1;                                       \
                BUF.l1[_j] = (short)f2bf(_x1 - bf2f(_h1));                     \
            }                                                                  \
        }                                                                      \
    } while (0)

#define LOADM(TILE, DST)                                                       \
    do {                                                                       \
        const int _tt = (TILE) > NT - 1 ? NT - 1 : (TILE);                     \
        _Pragma("unroll")                                                      \
        for (int _i = 0; _i < 4; ++_i) {                                       \
            const int _row = lg * 4 + _i;                                      \
            DST[_i] = s_mask[w][_row][(_tt * 16 + lr) ^ (_row << 2)];          \
        }                                                                      \
    } while (0)

#define PHASE(TILE, KCUR, KPRE, MCUR, MNXT)                                    \
    do {                                                                       \
        LOADK((TILE) + 2, KPRE);                                               \
        LOADM((TILE) + 1, MNXT);                                               \
        f32x4 _a1 = {0.f, 0.f, 0.f, 0.f};                                      \
        f32x4 _a2 = {0.f, 0.f, 0.f, 0.f};                                      \
        f32x4 _a3 = {0.f, 0.f, 0.f, 0.f};                                      \
        _a1 = __builtin_amdgcn_mfma_f32_16x16x32_bf16(ah0, KCUR.l0, _a1, 0, 0, 0);\
        _a2 = __builtin_amdgcn_mfma_f32_16x16x32_bf16(al0, KCUR.h0, _a2, 0, 0, 0);\
        _a3 = __builtin_amdgcn_mfma_f32_16x16x32_bf16(ah0, KCUR.h0, _a3, 0, 0, 0);\
        _a1 = __builtin_amdgcn_mfma_f32_16x16x32_bf16(ah1, KCUR.l1, _a1, 0, 0, 0);\
        _a2 = __builtin_amdgcn_mfma_f32_16x16x32_bf16(al1, KCUR.h1, _a2, 0, 0, 0);\
        _a3 = __builtin_amdgcn_mfma_f32_16x16x32_bf16(ah1, KCUR.h1, _a3, 0, 0, 0);\
        const f32x4 _s = (_a1 + _a2) + _a3;                                    \
        float _e[4];                                                           \
        _Pragma("unroll")                                                      \
        for (int _i = 0; _i < 4; ++_i) {                                       \
            const float _v = MCUR[_i] ? exp2f(_s[_i]) : 0.f;                   \
            _e[_i] = _v;                                                       \
            psum[_i] += _v;                                                    \
        }                                                                      \
        sc[2 * (TILE)    ] = (unsigned)f2bf(_e[0]) | ((unsigned)f2bf(_e[1]) << 16);\
        sc[2 * (TILE) + 1] = (unsigned)f2bf(_e[2]) | ((unsigned)f2bf(_e[3]) << 16);\
    } while (0)

    unsigned sc[NT * 2];              // packed bf16 exp values (32 VGPR)
    float psum[4] = {0.f, 0.f, 0.f, 0.f};

    KS kA, kB, kC, kD;
    unsigned char m0[4], m1[4];
    LOADK(0, kA);
    LOADK(1, kB);
    LOADM(0, m0);

    #pragma unroll
    for (int it = 0; it < 4; ++it) {
        PHASE(4 * it + 0, kA, kC, m0, m1);
        PHASE(4 * it + 1, kB, kD, m1, m0);
        PHASE(4 * it + 2, kC, kA, m0, m1);
        PHASE(4 * it + 3, kD, kB, m1, m0);
    }
#undef PHASE
#undef LOADM
#undef LOADK

    // ---- row sums: shfl within 16-lane row groups, LDS across 8 waves
    #pragma unroll
    for (int i = 0; i < 4; ++i) {
        float s = psum[i];
        s += __shfl_xor(s, 1, 64);
        s += __shfl_xor(s, 2, 64);
        s += __shfl_xor(s, 4, 64);
        s += __shfl_xor(s, 8, 64);
        psum[i] = s;
    }
    if (lr == 0) {
        #pragma unroll
        for (int i = 0; i < 4; ++i)
            s_red[w][lg * 4 + i] = psum[i];
    }
    __syncthreads();

    float rinv[4];
    #pragma unroll
    for (int i = 0; i < 4; ++i) {
        float tot = 0.f;
        #pragma unroll
        for (int ww = 0; ww < 8; ++ww)
            tot += s_red[ww][lg * 4 + i];
        rinv[i] = 1.0f / tot;
    }

    // ---- unpack, normalize, store
    #pragma unroll
    for (int nt = 0; nt < NT; ++nt) {
        const int n0 = nt * 16;
        const unsigned p01 = sc[2 * nt];
        const unsigned p23 = sc[2 * nt + 1];
        orow[0][n0] = bf2f((unsigned short)(p01 & 0xffffu))  * rinv[0];
        orow[1][n0] = bf2f((unsigned short)(p01 >> 16))      * rinv[1];
        orow[2][n0] = bf2f((unsigned short)(p23 & 0xffffu))  * rinv[2];
        orow[3][n0] = bf2f((unsigned short)(p23 >> 16))      * rinv[3];
    }
}

extern "C" void kernel_launch(void* const* d_in, const int* in_sizes, int n_in,
                              void* d_out, int out_size, void* d_ws, size_t ws_size,
                              hipStream_t stream) {
    const float* q    = (const float*)d_in[0];
    const float* k    = (const float*)d_in[1];
    const int*   mask = (const int*)d_in[2];
    float*       out  = (float*)d_out;

    const size_t KE   = (size_t)BB * SKL * DD;   // 4.19M elems
    const size_t NEED = KE * 4;                  // kh + kl (bf16 each)

    dim3 grid(4096);   // 1-D, XCD-swizzled in-kernel; 8 waves each

    if (ws_size >= NEED) {
        unsigned short* khp = (unsigned short*)d_ws;
        unsigned short* klp = khp + KE;
        split_k<<<1024, 256, 0, stream>>>(k, khp, klp, (int)(KE / 4));
        sdpa_fused<true><<<grid, 512, 0, stream>>>(q, k, mask, khp, klp, out);
    } else {
        sdpa_fused<false><<<grid, 512, 0, stream>>>(q, k, mask, nullptr, nullptr, out);
    }
}